// Round 6
// baseline (499.122 us; speedup 1.0000x reference)
//
#include <hip/hip_runtime.h>
#include <hip/hip_cooperative_groups.h>

namespace cg = cooperative_groups;

#define GROUP 8
#define BS 4096
#define CH 512
#define PW 32
#define NPANEL 16

typedef __attribute__((ext_vector_type(4))) float f32x4;
typedef __attribute__((ext_vector_type(8))) short bf16x8;
typedef __attribute__((ext_vector_type(8))) unsigned short u16x8;
typedef unsigned short u16;

static __device__ __forceinline__ u16 f2bf(float f) {
    unsigned int u = __builtin_bit_cast(unsigned int, f);
    u += 0x7FFFu + ((u >> 16) & 1u);   // RNE
    return (u16)(u >> 16);
}
static __device__ __forceinline__ float bf2f(u16 h) {
    return __builtin_bit_cast(float, (unsigned int)h << 16);
}
static __device__ __forceinline__ void split8(const float* v, bf16x8& h, bf16x8& l) {
#pragma unroll
    for (int j = 0; j < 8; ++j) {
        u16 hu = f2bf(v[j]);
        h[j] = (short)hu;
        l[j] = (short)f2bf(v[j] - bf2f(hu));
    }
}
#define MFMA(a, b, c) __builtin_amdgcn_mfma_f32_16x16x32_bf16(a, b, c, 0, 0, 0)

typedef const __attribute__((address_space(1))) void* gas_t;
typedef __attribute__((address_space(3))) void* las_t;
static __device__ __forceinline__ void gload16(const void* g, void* l) {
    __builtin_amdgcn_global_load_lds((gas_t)g, (las_t)l, 16, 0, 0);
}

// LDS union blob offsets (bytes)
#define SM_YLDS  0          // float [32][516] = 66048
#define SM_SP    66048      // float [4][32][36] = 18432
#define SM_SLS   84480      // float [32][36] = 4608
#define SM_TLS   89088      // float [32][36] = 4608
#define SM_BETA  93696      // float [32] = 128
#define SM_TOTAL 93824
// combine aliases (reuse same blob)
#define SM_MAH   0          // u16 [16][520] = 16640
#define SM_MAL   16640      // u16 [16][520] = 16640
#define SM_CL    33280      // float [16][260] = 16640

// ---------------------------------------------------------------------------
// Phase: per-32-panel prep (round-5 verified body)
// ---------------------------------------------------------------------------
static __device__ __forceinline__ void panelprep_phase(char* smem, int bid,
        const float* __restrict__ w, u16* Yh, u16* Yl, u16* Mth, u16* Mtl) {
    float (*Ylds)[516]     = (float(*)[516])(smem + SM_YLDS);
    float (*Sp)[PW][36]    = (float(*)[PW][36])(smem + SM_SP);
    float (*S_ls)[36]      = (float(*)[36])(smem + SM_SLS);
    float (*T_ls)[36]      = (float(*)[36])(smem + SM_TLS);
    float* betaL           = (float*)(smem + SM_BETA);

    int t    = threadIdx.x;
    int lane = t & 63;
    int wv   = t >> 6;
    int fr   = lane & 15;
    int kg   = lane >> 4;
    int g    = bid >> 4;
    int p    = bid & 15;
    int i0   = p * PW;

    const float* wg = w + (size_t)g * CH * CH;
    for (int idx4 = t; idx4 < 4096; idx4 += 256) {
        int c = idx4 >> 3, f4 = idx4 & 7;
        float4 v = *(const float4*)(wg + (size_t)c * CH + i0 + f4 * 4);
        Ylds[f4 * 4 + 0][c] = v.x;
        Ylds[f4 * 4 + 1][c] = v.y;
        Ylds[f4 * 4 + 2][c] = v.z;
        Ylds[f4 * 4 + 3][c] = v.w;
    }
    __syncthreads();

    {
        f32x4 sacc[2][2];
#pragma unroll
        for (int a = 0; a < 2; ++a)
#pragma unroll
            for (int b = 0; b < 2; ++b)
#pragma unroll
                for (int z = 0; z < 4; ++z) sacc[a][b][z] = 0.f;
#pragma unroll
        for (int kki = 0; kki < 4; ++kki) {
            int kk = 4 * wv + kki;
            bf16x8 fh[2], fl[2];
#pragma unroll
            for (int h = 0; h < 2; ++h) {
                float a8[8];
                const float* src = &Ylds[h * 16 + fr][kk * 32 + kg * 8];
#pragma unroll
                for (int j = 0; j < 8; ++j) a8[j] = src[j];
                split8(a8, fh[h], fl[h]);
            }
#pragma unroll
            for (int a = 0; a < 2; ++a)
#pragma unroll
                for (int b = 0; b < 2; ++b) {
                    sacc[a][b] = MFMA(fh[a], fh[b], sacc[a][b]);
                    sacc[a][b] = MFMA(fh[a], fl[b], sacc[a][b]);
                    sacc[a][b] = MFMA(fl[a], fh[b], sacc[a][b]);
                }
        }
#pragma unroll
        for (int a = 0; a < 2; ++a)
#pragma unroll
            for (int b = 0; b < 2; ++b)
#pragma unroll
                for (int j = 0; j < 4; ++j)
                    Sp[wv][a * 16 + kg * 4 + j][b * 16 + fr] = sacc[a][b][j];
    }
    __syncthreads();
    for (int idx = t; idx < PW * PW; idx += 256) {
        int r = idx >> 5, c = idx & 31;
        S_ls[r][c] = Sp[0][r][c] + Sp[1][r][c] + Sp[2][r][c] + Sp[3][r][c];
    }
    __syncthreads();
    if (t < PW) betaL[t] = 2.0f / S_ls[t][t];
    for (int idx = t; idx < PW * 36; idx += 256) ((float*)T_ls)[idx] = 0.f;
    __syncthreads();
    if (t < PW) T_ls[t][t] = betaL[t];
    __syncthreads();
    for (int k = 1; k < PW; ++k) {
        if (t < k) {
            float acc = 0.f;
            for (int j = t; j < k; ++j) acc += T_ls[t][j] * S_ls[j][k];
            T_ls[t][k] = -betaL[k] * acc;
        }
        __syncthreads();
    }

    bf16x8 tbh[2], tbl[2];
#pragma unroll
    for (int cf = 0; cf < 2; ++cf) {
        float t8[8];
        const float* src = &T_ls[cf * 16 + fr][kg * 8];
#pragma unroll
        for (int j = 0; j < 8; ++j) t8[j] = src[j];
        split8(t8, tbh[cf], tbl[cf]);
    }
#pragma unroll
    for (int rfi = 0; rfi < 8; ++rfi) {
        int rf = 8 * wv + rfi;
        float a8[8];
#pragma unroll
        for (int j = 0; j < 8; ++j) a8[j] = Ylds[kg * 8 + j][rf * 16 + fr];
        bf16x8 ah, al;
        split8(a8, ah, al);
#pragma unroll
        for (int cf = 0; cf < 2; ++cf) {
            f32x4 m;
#pragma unroll
            for (int z = 0; z < 4; ++z) m[z] = 0.f;
            m = MFMA(ah, tbh[cf], m);
            m = MFMA(ah, tbl[cf], m);
            m = MFMA(al, tbh[cf], m);
#pragma unroll
            for (int j = 0; j < 4; ++j) {
                int c = rf * 16 + kg * 4 + j;
                int i = cf * 16 + fr;
                size_t off = ((size_t)g * CH + c) * CH + (i0 + i);
                u16 hu = f2bf(m[j]);
                Mth[off] = hu;
                Mtl[off] = f2bf(m[j] - bf2f(hu));
            }
        }
    }

    for (int idx = t; idx < PW * CH; idx += 256) {
        int r = idx >> 9, c = idx & 511;
        float v = Ylds[r][c];
        size_t off = ((size_t)g * CH + i0 + r) * CH + c;
        u16 hu = f2bf(v);
        Yh[off] = hu;
        Yl[off] = f2bf(v - bf2f(hu));
    }
}

// ---------------------------------------------------------------------------
// Phase: WY merge level (round-5 verified body)
// ---------------------------------------------------------------------------
template<int W>
static __device__ __forceinline__ void combine_phase(char* smem, int bid,
        const u16* Yh, const u16* Yl, u16* Mth, u16* Mtl) {
    u16 (*MAh)[520]  = (u16(*)[520])(smem + SM_MAH);
    u16 (*MAl)[520]  = (u16(*)[520])(smem + SM_MAL);
    float (*Cl)[260] = (float(*)[260])(smem + SM_CL);

    int t = threadIdx.x, lane = t & 63, wv = t >> 6;
    int fr = lane & 15, kg = lane >> 4;
    int g  = bid >> 4;
    int sg = bid & 15;
    constexpr int SP = W / 16;
    int q  = sg / SP, rs = sg % SP;
    int i_top0 = 2 * q * W + rs * 16;
    int i_bot0 = 2 * q * W + W;

    const u16* Yh_g = Yh + (size_t)g * CH * CH;
    const u16* Yl_g = Yl + (size_t)g * CH * CH;
    u16* Mth_g = Mth + (size_t)g * CH * CH;
    u16* Mtl_g = Mtl + (size_t)g * CH * CH;

    for (int idx = t; idx < 1024; idx += 256) {
        int c = idx >> 1, ch = idx & 1;
        bf16x8 hv = *(const bf16x8*)(Mth_g + (size_t)c * CH + i_top0 + ch * 8);
        bf16x8 lv = *(const bf16x8*)(Mtl_g + (size_t)c * CH + i_top0 + ch * 8);
#pragma unroll
        for (int j = 0; j < 8; ++j) {
            MAh[ch * 8 + j][c] = (u16)hv[j];
            MAl[ch * 8 + j][c] = (u16)lv[j];
        }
    }
    __syncthreads();

    constexpr int NF = W / 16;
    constexpr int CPW = (NF + 3) / 4;
    f32x4 accC[CPW];
#pragma unroll
    for (int nfi = 0; nfi < CPW; ++nfi)
#pragma unroll
        for (int z = 0; z < 4; ++z) accC[nfi][z] = 0.f;

    for (int ks = 0; ks < 16; ++ks) {
        bf16x8 ah = *(const bf16x8*)&MAh[fr][ks * 32 + kg * 8];
        bf16x8 al = *(const bf16x8*)&MAl[fr][ks * 32 + kg * 8];
#pragma unroll
        for (int nfi = 0; nfi < CPW; ++nfi) {
            int nf = wv + 4 * nfi;
            if (nf < NF) {
                size_t yo = (size_t)(i_bot0 + nf * 16 + fr) * CH + ks * 32 + kg * 8;
                bf16x8 bh = *(const bf16x8*)(Yh_g + yo);
                bf16x8 bl = *(const bf16x8*)(Yl_g + yo);
                accC[nfi] = MFMA(ah, bh, accC[nfi]);
                accC[nfi] = MFMA(ah, bl, accC[nfi]);
                accC[nfi] = MFMA(al, bh, accC[nfi]);
            }
        }
    }
#pragma unroll
    for (int nfi = 0; nfi < CPW; ++nfi) {
        int nf = wv + 4 * nfi;
        if (nf < NF)
#pragma unroll
            for (int jj = 0; jj < 4; ++jj)
                Cl[kg * 4 + jj][nf * 16 + fr] = accC[nfi][jj];
    }
    __syncthreads();

    f32x4 accU[8];
#pragma unroll
    for (int ni = 0; ni < 8; ++ni)
#pragma unroll
        for (int z = 0; z < 4; ++z) accU[ni][z] = 0.f;

    for (int ks2 = 0; ks2 < W / 32; ++ks2) {
        float a8[8];
#pragma unroll
        for (int j = 0; j < 8; ++j) a8[j] = Cl[fr][ks2 * 32 + kg * 8 + j];
        bf16x8 ah2, al2;
        split8(a8, ah2, al2);
#pragma unroll
        for (int ni = 0; ni < 8; ++ni) {
            int c = (wv * 8 + ni) * 16 + fr;
            size_t mo = (size_t)c * CH + i_bot0 + ks2 * 32 + kg * 8;
            bf16x8 bh = *(const bf16x8*)(Mth_g + mo);
            bf16x8 bl = *(const bf16x8*)(Mtl_g + mo);
            accU[ni] = MFMA(ah2, bh, accU[ni]);
            accU[ni] = MFMA(ah2, bl, accU[ni]);
            accU[ni] = MFMA(al2, bh, accU[ni]);
        }
    }
#pragma unroll
    for (int ni = 0; ni < 8; ++ni) {
        int c = (wv * 8 + ni) * 16 + fr;
#pragma unroll
        for (int jj = 0; jj < 4; ++jj) {
            int il = kg * 4 + jj;
            float ma = bf2f(MAh[il][c]) + bf2f(MAl[il][c]);
            float m2 = ma - accU[ni][jj];
            u16 hu = f2bf(m2);
            MAh[il][c] = hu;
            MAl[il][c] = f2bf(m2 - bf2f(hu));
        }
    }
    __syncthreads();

    for (int idx = t; idx < 1024; idx += 256) {
        int c = idx >> 1, ch = idx & 1;
        bf16x8 hv, lv;
#pragma unroll
        for (int j = 0; j < 8; ++j) {
            hv[j] = (short)MAh[ch * 8 + j][c];
            lv[j] = (short)MAl[ch * 8 + j][c];
        }
        *(bf16x8*)(Mth_g + (size_t)c * CH + i_top0 + ch * 8) = hv;
        *(bf16x8*)(Mtl_g + (size_t)c * CH + i_top0 + ch * 8) = lv;
    }
}

// ---------------------------------------------------------------------------
// Phase: Qt[g][d][c] = [I - w*M]^T  (round-5 verified body; 256 blocks)
// ---------------------------------------------------------------------------
static __device__ __forceinline__ void qbuild2_phase(int bid,
        const float* __restrict__ w, const u16* Mth, const u16* Mtl, u16* Qt) {
    int t = threadIdx.x, lane = t & 63, wv = t >> 6;
    int fr = lane & 15, kg = lane >> 4;
    int g  = bid >> 5;
    int tm = (bid >> 2) & 7, tn = bid & 3;
    int c0 = tm * 64;
    int d0 = tn * 128 + wv * 32;

    const float* wg = w + (size_t)g * CH * CH;
    const u16* Mth_g = Mth + (size_t)g * CH * CH;
    const u16* Mtl_g = Mtl + (size_t)g * CH * CH;
    u16* Qt_g = Qt + (size_t)g * CH * CH;

    f32x4 acc[4][2];
#pragma unroll
    for (int mi = 0; mi < 4; ++mi)
#pragma unroll
        for (int ni = 0; ni < 2; ++ni)
#pragma unroll
            for (int z = 0; z < 4; ++z) acc[mi][ni][z] = 0.f;

    for (int ks = 0; ks < 16; ++ks) {
        bf16x8 ah[4], al[4], bh[2], bl[2];
#pragma unroll
        for (int mi = 0; mi < 4; ++mi) {
            const float* src = wg + (size_t)(c0 + mi * 16 + fr) * CH + ks * 32 + kg * 8;
            float4 v0 = *(const float4*)src;
            float4 v1 = *(const float4*)(src + 4);
            float a8[8] = {v0.x, v0.y, v0.z, v0.w, v1.x, v1.y, v1.z, v1.w};
            split8(a8, ah[mi], al[mi]);
        }
#pragma unroll
        for (int ni = 0; ni < 2; ++ni) {
            size_t mo = (size_t)(d0 + ni * 16 + fr) * CH + ks * 32 + kg * 8;
            bh[ni] = *(const bf16x8*)(Mth_g + mo);
            bl[ni] = *(const bf16x8*)(Mtl_g + mo);
        }
#pragma unroll
        for (int mi = 0; mi < 4; ++mi)
#pragma unroll
            for (int ni = 0; ni < 2; ++ni) {
                acc[mi][ni] = MFMA(ah[mi], bh[ni], acc[mi][ni]);
                acc[mi][ni] = MFMA(ah[mi], bl[ni], acc[mi][ni]);
                acc[mi][ni] = MFMA(al[mi], bh[ni], acc[mi][ni]);
            }
    }
#pragma unroll
    for (int mi = 0; mi < 4; ++mi)
#pragma unroll
        for (int ni = 0; ni < 2; ++ni) {
            int cb = c0 + mi * 16 + kg * 4;
            int d  = d0 + ni * 16 + fr;
            ushort4 h4;
            h4.x = f2bf(((cb + 0 == d) ? 1.0f : 0.0f) - acc[mi][ni][0]);
            h4.y = f2bf(((cb + 1 == d) ? 1.0f : 0.0f) - acc[mi][ni][1]);
            h4.z = f2bf(((cb + 2 == d) ? 1.0f : 0.0f) - acc[mi][ni][2]);
            h4.w = f2bf(((cb + 3 == d) ? 1.0f : 0.0f) - acc[mi][ni][3]);
            *(ushort4*)(Qt_g + (size_t)d * CH + cb) = h4;
        }
}

// ---------------------------------------------------------------------------
// Phase: x fp32 -> bf16 cast, chunk c of 5 (blocks 128..255)
// ---------------------------------------------------------------------------
static __device__ __forceinline__ void xcast_phase(int c, const float* __restrict__ x,
                                                   u16* __restrict__ xb, int bid, int t) {
    const int TOT8 = GROUP * BS * CH / 8;           // 2097152 8-elem units
    int i0 = (int)(((long long)TOT8 * c) / 5);
    int i1 = (int)(((long long)TOT8 * (c + 1)) / 5);
    for (int i = i0 + (bid - 128) * 256 + t; i < i1; i += 128 * 256) {
        const float4* s = (const float4*)(x + (size_t)i * 8);
        float4 a = s[0], b = s[1];
        u16x8 o;
        o[0] = f2bf(a.x); o[1] = f2bf(a.y); o[2] = f2bf(a.z); o[3] = f2bf(a.w);
        o[4] = f2bf(b.x); o[5] = f2bf(b.y); o[6] = f2bf(b.z); o[7] = f2bf(b.w);
        *(u16x8*)(xb + (size_t)i * 8) = o;
    }
}

// ---------------------------------------------------------------------------
// Cooperative fused prep kernel: 256 blocks x 256 thr.
// ---------------------------------------------------------------------------
__global__ __launch_bounds__(256) void k_prep(const float* __restrict__ w,
                                              const float* __restrict__ x,
                                              u16* Yh, u16* Yl, u16* Mth, u16* Mtl,
                                              u16* Qt, u16* xb, int do_xcast) {
    __shared__ alignas(16) char smem[SM_TOTAL];
    cg::grid_group gg = cg::this_grid();
    int bid = blockIdx.x, t = threadIdx.x;

    if (bid < 128) panelprep_phase(smem, bid, w, Yh, Yl, Mth, Mtl);
    else if (do_xcast) xcast_phase(0, x, xb, bid, t);
    __threadfence(); gg.sync();

    if (bid < 128) combine_phase<32>(smem, bid, Yh, Yl, Mth, Mtl);
    else if (do_xcast) xcast_phase(1, x, xb, bid, t);
    __threadfence(); gg.sync();

    if (bid < 128) combine_phase<64>(smem, bid, Yh, Yl, Mth, Mtl);
    else if (do_xcast) xcast_phase(2, x, xb, bid, t);
    __threadfence(); gg.sync();

    if (bid < 128) combine_phase<128>(smem, bid, Yh, Yl, Mth, Mtl);
    else if (do_xcast) xcast_phase(3, x, xb, bid, t);
    __threadfence(); gg.sync();

    if (bid < 128) combine_phase<256>(smem, bid, Yh, Yl, Mth, Mtl);
    else if (do_xcast) xcast_phase(4, x, xb, bid, t);
    __threadfence(); gg.sync();

    qbuild2_phase(bid, w, Mth, Mtl, Qt);
}

// ---------------------------------------------------------------------------
// GEMM (m97-style): out[g] = x[g] @ Q[g]; A = xb bf16, B = Qt bf16,
// both staged via global_load_lds width-16 into linear LDS. 128x128, BK=32.
// ---------------------------------------------------------------------------
__global__ __launch_bounds__(256) void k_gemm2(const u16* __restrict__ xb,
                                               const u16* __restrict__ Qt,
                                               float* __restrict__ out) {
    __shared__ u16 Ab[128 * 32];
    __shared__ u16 Bb[128 * 32];

    int bid = blockIdx.x;
    int g  = bid >> 7;
    int tn = (bid >> 5) & 3;
    int tm = bid & 31;

    int t    = threadIdx.x;
    int lane = t & 63;
    int wv   = t >> 6;
    int wr   = wv >> 1, wc = wv & 1;
    int fr   = lane & 15, kg = lane >> 4;

    const u16* xg  = xb + (size_t)g * BS * CH + (size_t)tm * 128 * CH;
    const u16* Qtg = Qt + (size_t)g * CH * CH + (size_t)tn * 128 * CH;
    float* og = out + (size_t)g * BS * CH + (size_t)tm * 128 * CH + (size_t)tn * 128;

    f32x4 acc[4][4];
#pragma unroll
    for (int mi = 0; mi < 4; ++mi)
#pragma unroll
        for (int ni = 0; ni < 4; ++ni)
#pragma unroll
            for (int z = 0; z < 4; ++z) acc[mi][ni][z] = 0.f;

    int srow = lane >> 2;        // 0..15 within 16-row segment
    int scol = (lane & 3) * 8;   // bf16 elem offset within 32-wide K

    for (int ks = 0; ks < 16; ++ks) {
        int k0 = ks * 32;
        __syncthreads();
        // stage A,B: wave wv fills segments 2wv, 2wv+1 (1 KB each)
#pragma unroll
        for (int si = 0; si < 2; ++si) {
            int s = wv * 2 + si;
            int row = s * 16 + srow;
            gload16(xg  + (size_t)row * CH + k0 + scol, &Ab[s * 512]);
            gload16(Qtg + (size_t)row * CH + k0 + scol, &Bb[s * 512]);
        }
        __syncthreads();   // drains vmcnt(0): LDS now valid

        bf16x8 af[4], bfr[4];
#pragma unroll
        for (int mi = 0; mi < 4; ++mi)
            af[mi] = *(const bf16x8*)&Ab[(wr * 64 + mi * 16 + fr) * 32 + kg * 8];
#pragma unroll
        for (int ni = 0; ni < 4; ++ni)
            bfr[ni] = *(const bf16x8*)&Bb[(wc * 64 + ni * 16 + fr) * 32 + kg * 8];
#pragma unroll
        for (int mi = 0; mi < 4; ++mi)
#pragma unroll
            for (int ni = 0; ni < 4; ++ni)
                acc[mi][ni] = MFMA(af[mi], bfr[ni], acc[mi][ni]);
    }

    int rg = lane >> 4;
#pragma unroll
    for (int mi = 0; mi < 4; ++mi)
#pragma unroll
        for (int ni = 0; ni < 4; ++ni)
#pragma unroll
            for (int rj = 0; rj < 4; ++rj) {
                int grow = wr * 64 + mi * 16 + rg * 4 + rj;
                int gcol = wc * 64 + ni * 16 + fr;
                og[(size_t)grow * CH + gcol] = acc[mi][ni][rj];
            }
}

// ---------------------------------------------------------------------------
// Fallback GEMM (fp32 A with in-staging convert) — round-5 verified.
// ---------------------------------------------------------------------------
#define LDP 40
__global__ __launch_bounds__(256) void k_gemm_f32(const float* __restrict__ x,
                                                  const u16* __restrict__ Qt,
                                                  float* __restrict__ out) {
    __shared__ u16 Al[128 * LDP];
    __shared__ u16 Bl[128 * LDP];

    int bid = blockIdx.x;
    int g  = bid >> 7;
    int tn = (bid >> 5) & 3;
    int tm = bid & 31;

    int t    = threadIdx.x;
    int lane = t & 63;
    int w    = t >> 6;
    int wr   = w >> 1, wc = w & 1;

    const float* xg = x + (size_t)g * BS * CH + (size_t)tm * 128 * CH;
    const u16* Qtg = Qt + (size_t)g * CH * CH + (size_t)tn * 128 * CH;
    float* og = out + (size_t)g * BS * CH + (size_t)tm * 128 * CH + (size_t)tn * 128;

    f32x4 acc[4][4];
#pragma unroll
    for (int mi = 0; mi < 4; ++mi)
#pragma unroll
        for (int ni = 0; ni < 4; ++ni)
#pragma unroll
            for (int z = 0; z < 4; ++z) acc[mi][ni][z] = 0.f;

    int a_k4 = t & 7;
    int a_r  = t >> 3;
    int b_n  = t & 127;
    int b_kh = t >> 7;
    int fr = lane & 15, kg = lane >> 4;

    for (int ks = 0; ks < 16; ++ks) {
        int k0 = ks * 32;
        __syncthreads();
#pragma unroll
        for (int rr = 0; rr < 4; ++rr) {
            int r = a_r + 32 * rr;
            float4 v = *(const float4*)(xg + (size_t)r * CH + k0 + a_k4 * 4);
            ushort4 h;
            h.x = f2bf(v.x); h.y = f2bf(v.y); h.z = f2bf(v.z); h.w = f2bf(v.w);
            *(ushort4*)(&Al[r * LDP + a_k4 * 4]) = h;
        }
        {
            const u16* src = Qtg + (size_t)b_n * CH + k0 + b_kh * 16;
            u16x8 lo = *(const u16x8*)src;
            u16x8 hi = *(const u16x8*)(src + 8);
            *(u16x8*)(&Bl[b_n * LDP + b_kh * 16]) = lo;
            *(u16x8*)(&Bl[b_n * LDP + b_kh * 16 + 8]) = hi;
        }
        __syncthreads();
        bf16x8 af[4], bfr[4];
#pragma unroll
        for (int mi = 0; mi < 4; ++mi)
            af[mi] = *(const bf16x8*)(&Al[(wr * 64 + mi * 16 + fr) * LDP + kg * 8]);
#pragma unroll
        for (int ni = 0; ni < 4; ++ni)
            bfr[ni] = *(const bf16x8*)(&Bl[(wc * 64 + ni * 16 + fr) * LDP + kg * 8]);
#pragma unroll
        for (int mi = 0; mi < 4; ++mi)
#pragma unroll
            for (int ni = 0; ni < 4; ++ni)
                acc[mi][ni] = MFMA(af[mi], bfr[ni], acc[mi][ni]);
    }

    int rg = lane >> 4;
#pragma unroll
    for (int mi = 0; mi < 4; ++mi)
#pragma unroll
        for (int ni = 0; ni < 4; ++ni)
#pragma unroll
            for (int rj = 0; rj < 4; ++rj) {
                int grow = wr * 64 + mi * 16 + rg * 4 + rj;
                int gcol = wc * 64 + ni * 16 + fr;
                og[(size_t)grow * CH + gcol] = acc[mi][ni][rj];
            }
}

// ---------------------------------------------------------------------------
extern "C" void kernel_launch(void* const* d_in, const int* in_sizes, int n_in,
                              void* d_out, int out_size, void* d_ws, size_t ws_size,
                              hipStream_t stream) {
    const float* x = (const float*)d_in[0];   // (8, 4096, 512)
    const float* w = (const float*)d_in[1];   // (8, 512, 512)
    float* out = (float*)d_out;

    // scratch carved from d_out (64 MiB; all dead before GEMM writes it):
    char* ob = (char*)d_out;
    u16* Yh  = (u16*)ob;                      // [0, 4MB)
    u16* Yl  = (u16*)(ob + (4u  << 20));      // [4, 8)
    u16* Mth = (u16*)(ob + (8u  << 20));      // [8, 12)
    u16* Mtl = (u16*)(ob + (12u << 20));      // [12, 16)

    // d_ws: xb (32 MB bf16 x) + Qt (4 MB) when it fits; else Qt only.
    int fat = (ws_size >= ((32u << 20) + (4u << 20))) ? 1 : 0;
    u16* xbp = (u16*)d_ws;
    u16* Qt  = fat ? (u16*)((char*)d_ws + (32u << 20)) : (u16*)d_ws;

    void* args[] = {(void*)&w, (void*)&x, (void*)&Yh, (void*)&Yl, (void*)&Mth,
                    (void*)&Mtl, (void*)&Qt, (void*)&xbp, (void*)&fat};
    hipLaunchCooperativeKernel((void*)k_prep, dim3(256), dim3(256), args, 0, stream);

    if (fat)
        k_gemm2<<<dim3(1024), dim3(256), 0, stream>>>(xbp, Qt, out);
    else
        k_gemm_f32<<<dim3(1024), dim3(256), 0, stream>>>(x, Qt, out);
}

// Round 7
// 190.038 us; speedup vs baseline: 2.6264x; 2.6264x over previous
//
#include <hip/hip_runtime.h>

#define GROUP 8
#define BS 4096
#define CH 512
#define PW 32
#define NPANEL 16

typedef __attribute__((ext_vector_type(4))) float f32x4;
typedef __attribute__((ext_vector_type(8))) short bf16x8;
typedef __attribute__((ext_vector_type(8))) unsigned short u16x8;
typedef unsigned short u16;

static __device__ __forceinline__ u16 f2bf(float f) {
    unsigned int u = __builtin_bit_cast(unsigned int, f);
    u += 0x7FFFu + ((u >> 16) & 1u);   // RNE
    return (u16)(u >> 16);
}
static __device__ __forceinline__ float bf2f(u16 h) {
    return __builtin_bit_cast(float, (unsigned int)h << 16);
}
static __device__ __forceinline__ void split8(const float* v, bf16x8& h, bf16x8& l) {
#pragma unroll
    for (int j = 0; j < 8; ++j) {
        u16 hu = f2bf(v[j]);
        h[j] = (short)hu;
        l[j] = (short)f2bf(v[j] - bf2f(hu));
    }
}
#define MFMA(a, b, c) __builtin_amdgcn_mfma_f32_16x16x32_bf16(a, b, c, 0, 0, 0)

typedef const __attribute__((address_space(1))) void* gas_t;
typedef __attribute__((address_space(3))) void* las_t;
static __device__ __forceinline__ void gload16(const void* g, void* l) {
    __builtin_amdgcn_global_load_lds((gas_t)g, (las_t)l, 16, 0, 0);
}

// ---------------------------------------------------------------------------
// Kernel 1: per-32-panel prep, 512 thr (8 waves -> 2 waves/SIMD).
// Blocks 0..127: prep. Blocks 128..1151 (fat only): x fp32->bf16 cast.
// ---------------------------------------------------------------------------
__global__ __launch_bounds__(512) void k_panelprep(const float* __restrict__ w,
                                                   const float* __restrict__ x,
                                                   u16* __restrict__ Yh,
                                                   u16* __restrict__ Yl,
                                                   u16* __restrict__ Mth,
                                                   u16* __restrict__ Mtl,
                                                   u16* __restrict__ xb) {
    __shared__ float Ylds[PW][516];      // 66048 B
    __shared__ float Sp[8][PW][36];      // 36864 B
    __shared__ float S_ls[PW][36];
    __shared__ float T_ls[PW][36];
    __shared__ float betaL[PW];

    int bid = blockIdx.x;
    int t   = threadIdx.x;

    if (bid >= 128) {
        // ---- xcast: 1024 blocks x 512 thr, 4 iters each ----
        const int TOT8 = GROUP * BS * CH / 8;       // 2097152
        for (int i = (bid - 128) * 512 + t; i < TOT8; i += 1024 * 512) {
            const float4* s = (const float4*)(x + (size_t)i * 8);
            float4 a = s[0], b = s[1];
            u16x8 o;
            o[0] = f2bf(a.x); o[1] = f2bf(a.y); o[2] = f2bf(a.z); o[3] = f2bf(a.w);
            o[4] = f2bf(b.x); o[5] = f2bf(b.y); o[6] = f2bf(b.z); o[7] = f2bf(b.w);
            *(u16x8*)(xb + (size_t)i * 8) = o;
        }
        return;
    }

    int lane = t & 63;
    int wv   = t >> 6;           // 0..7
    int fr   = lane & 15;
    int kg   = lane >> 4;
    int g    = bid >> 4;
    int p    = bid & 15;
    int i0   = p * PW;

    // ---- stage Y[i][c] = w[g][c][i0+i] (transpose-read, 32x512) ----
    const float* wg = w + (size_t)g * CH * CH;
    for (int idx4 = t; idx4 < 4096; idx4 += 512) {
        int c = idx4 >> 3, f4 = idx4 & 7;
        float4 v = *(const float4*)(wg + (size_t)c * CH + i0 + f4 * 4);
        Ylds[f4 * 4 + 0][c] = v.x;
        Ylds[f4 * 4 + 1][c] = v.y;
        Ylds[f4 * 4 + 2][c] = v.z;
        Ylds[f4 * 4 + 3][c] = v.w;
    }
    __syncthreads();

    // ---- S = Y Y^T via split MFMA; wave wv covers kk = 2wv..2wv+1 ----
    {
        f32x4 sacc[2][2];
#pragma unroll
        for (int a = 0; a < 2; ++a)
#pragma unroll
            for (int b = 0; b < 2; ++b)
#pragma unroll
                for (int z = 0; z < 4; ++z) sacc[a][b][z] = 0.f;
#pragma unroll
        for (int kki = 0; kki < 2; ++kki) {
            int kk = 2 * wv + kki;
            bf16x8 fh[2], fl[2];
#pragma unroll
            for (int h = 0; h < 2; ++h) {
                float a8[8];
                const float* src = &Ylds[h * 16 + fr][kk * 32 + kg * 8];
#pragma unroll
                for (int j = 0; j < 8; ++j) a8[j] = src[j];
                split8(a8, fh[h], fl[h]);
            }
#pragma unroll
            for (int a = 0; a < 2; ++a)
#pragma unroll
                for (int b = 0; b < 2; ++b) {
                    sacc[a][b] = MFMA(fh[a], fh[b], sacc[a][b]);
                    sacc[a][b] = MFMA(fh[a], fl[b], sacc[a][b]);
                    sacc[a][b] = MFMA(fl[a], fh[b], sacc[a][b]);
                }
        }
#pragma unroll
        for (int a = 0; a < 2; ++a)
#pragma unroll
            for (int b = 0; b < 2; ++b)
#pragma unroll
                for (int j = 0; j < 4; ++j)
                    Sp[wv][a * 16 + kg * 4 + j][b * 16 + fr] = sacc[a][b][j];
    }
    __syncthreads();
    for (int idx = t; idx < PW * PW; idx += 512) {
        int r = idx >> 5, c = idx & 31;
        float s = 0.f;
#pragma unroll
        for (int q = 0; q < 8; ++q) s += Sp[q][r][c];
        S_ls[r][c] = s;
    }
    __syncthreads();
    if (t < PW) betaL[t] = 2.0f / S_ls[t][t];
    for (int idx = t; idx < PW * 36; idx += 512) ((float*)T_ls)[idx] = 0.f;
    __syncthreads();
    if (t < PW) T_ls[t][t] = betaL[t];
    __syncthreads();
    for (int k = 1; k < PW; ++k) {
        if (t < k) {
            float acc = 0.f;
            for (int j = t; j < k; ++j) acc += T_ls[t][j] * S_ls[j][k];
            T_ls[t][k] = -betaL[k] * acc;
        }
        __syncthreads();
    }

    // ---- M^T = Y^T * T^T (512x32, K=32): wave wv covers rf = 4wv..4wv+3 ----
    bf16x8 tbh[2], tbl[2];
#pragma unroll
    for (int cf = 0; cf < 2; ++cf) {
        float t8[8];
        const float* src = &T_ls[cf * 16 + fr][kg * 8];
#pragma unroll
        for (int j = 0; j < 8; ++j) t8[j] = src[j];
        split8(t8, tbh[cf], tbl[cf]);
    }
#pragma unroll
    for (int rfi = 0; rfi < 4; ++rfi) {
        int rf = 4 * wv + rfi;
        float a8[8];
#pragma unroll
        for (int j = 0; j < 8; ++j) a8[j] = Ylds[kg * 8 + j][rf * 16 + fr];
        bf16x8 ah, al;
        split8(a8, ah, al);
#pragma unroll
        for (int cf = 0; cf < 2; ++cf) {
            f32x4 m;
#pragma unroll
            for (int z = 0; z < 4; ++z) m[z] = 0.f;
            m = MFMA(ah, tbh[cf], m);
            m = MFMA(ah, tbl[cf], m);
            m = MFMA(al, tbh[cf], m);
#pragma unroll
            for (int j = 0; j < 4; ++j) {
                int c = rf * 16 + kg * 4 + j;
                int i = cf * 16 + fr;
                size_t off = ((size_t)g * CH + c) * CH + (i0 + i);
                u16 hu = f2bf(m[j]);
                Mth[off] = hu;
                Mtl[off] = f2bf(m[j] - bf2f(hu));
            }
        }
    }

    // ---- export Y panel bf16 hi/lo ----
    for (int idx = t; idx < PW * CH; idx += 512) {
        int r = idx >> 9, c = idx & 511;
        float v = Ylds[r][c];
        size_t off = ((size_t)g * CH + i0 + r) * CH + c;
        u16 hu = f2bf(v);
        Yh[off] = hu;
        Yl[off] = f2bf(v - bf2f(hu));
    }
}

// ---------------------------------------------------------------------------
// Kernel 2 (x4 levels): WY merge, 128 blocks x 512 thr (8 waves).
// M_top' = M_top - (M_top Y_bot^T) M_bot. In-place, race-free.
// ---------------------------------------------------------------------------
template<int W>
__global__ __launch_bounds__(512) void k_combine(const u16* __restrict__ Yh,
                                                 const u16* __restrict__ Yl,
                                                 u16* __restrict__ Mth,
                                                 u16* __restrict__ Mtl) {
    __shared__ u16 MAh[16][520];
    __shared__ u16 MAl[16][520];
    __shared__ float Cl[16][260];

    int t = threadIdx.x, lane = t & 63, wv = t >> 6;
    int fr = lane & 15, kg = lane >> 4;
    int g  = blockIdx.x >> 4;
    int sg = blockIdx.x & 15;
    constexpr int SP = W / 16;
    int q  = sg / SP, rs = sg % SP;
    int i_top0 = 2 * q * W + rs * 16;
    int i_bot0 = 2 * q * W + W;

    const u16* Yh_g = Yh + (size_t)g * CH * CH;
    const u16* Yl_g = Yl + (size_t)g * CH * CH;
    u16* Mth_g = Mth + (size_t)g * CH * CH;
    u16* Mtl_g = Mtl + (size_t)g * CH * CH;

    // ---- stage M_A strip transposed to row-major MA[i][c] (16 x 512) ----
    for (int idx = t; idx < 1024; idx += 512) {
        int c = idx >> 1, ch = idx & 1;
        bf16x8 hv = *(const bf16x8*)(Mth_g + (size_t)c * CH + i_top0 + ch * 8);
        bf16x8 lv = *(const bf16x8*)(Mtl_g + (size_t)c * CH + i_top0 + ch * 8);
#pragma unroll
        for (int j = 0; j < 8; ++j) {
            MAh[ch * 8 + j][c] = (u16)hv[j];
            MAl[ch * 8 + j][c] = (u16)lv[j];
        }
    }
    __syncthreads();

    // ---- C[i][jb] = sum_c MA[i][c] Ybot[jb][c]  (16 x W, K=512) ----
    constexpr int NF = W / 16;
    constexpr int CPW = (NF + 7) / 8;
    f32x4 accC[CPW];
#pragma unroll
    for (int nfi = 0; nfi < CPW; ++nfi)
#pragma unroll
        for (int z = 0; z < 4; ++z) accC[nfi][z] = 0.f;

    for (int ks = 0; ks < 16; ++ks) {
        bf16x8 ah = *(const bf16x8*)&MAh[fr][ks * 32 + kg * 8];
        bf16x8 al = *(const bf16x8*)&MAl[fr][ks * 32 + kg * 8];
#pragma unroll
        for (int nfi = 0; nfi < CPW; ++nfi) {
            int nf = wv + 8 * nfi;
            if (nf < NF) {
                size_t yo = (size_t)(i_bot0 + nf * 16 + fr) * CH + ks * 32 + kg * 8;
                bf16x8 bh = *(const bf16x8*)(Yh_g + yo);
                bf16x8 bl = *(const bf16x8*)(Yl_g + yo);
                accC[nfi] = MFMA(ah, bh, accC[nfi]);
                accC[nfi] = MFMA(ah, bl, accC[nfi]);
                accC[nfi] = MFMA(al, bh, accC[nfi]);
            }
        }
    }
#pragma unroll
    for (int nfi = 0; nfi < CPW; ++nfi) {
        int nf = wv + 8 * nfi;
        if (nf < NF)
#pragma unroll
            for (int jj = 0; jj < 4; ++jj)
                Cl[kg * 4 + jj][nf * 16 + fr] = accC[nfi][jj];
    }
    __syncthreads();

    // ---- U[i][c] = sum_j C[i][j] MB[j][c]  (16 x 512, K=W); M' = MA - U ----
    f32x4 accU[4];
#pragma unroll
    for (int ni = 0; ni < 4; ++ni)
#pragma unroll
        for (int z = 0; z < 4; ++z) accU[ni][z] = 0.f;

    for (int ks2 = 0; ks2 < W / 32; ++ks2) {
        float a8[8];
#pragma unroll
        for (int j = 0; j < 8; ++j) a8[j] = Cl[fr][ks2 * 32 + kg * 8 + j];
        bf16x8 ah2, al2;
        split8(a8, ah2, al2);
#pragma unroll
        for (int ni = 0; ni < 4; ++ni) {
            int c = (wv * 4 + ni) * 16 + fr;
            size_t mo = (size_t)c * CH + i_bot0 + ks2 * 32 + kg * 8;
            bf16x8 bh = *(const bf16x8*)(Mth_g + mo);
            bf16x8 bl = *(const bf16x8*)(Mtl_g + mo);
            accU[ni] = MFMA(ah2, bh, accU[ni]);
            accU[ni] = MFMA(ah2, bl, accU[ni]);
            accU[ni] = MFMA(al2, bh, accU[ni]);
        }
    }
#pragma unroll
    for (int ni = 0; ni < 4; ++ni) {
        int c = (wv * 4 + ni) * 16 + fr;
#pragma unroll
        for (int jj = 0; jj < 4; ++jj) {
            int il = kg * 4 + jj;
            float ma = bf2f(MAh[il][c]) + bf2f(MAl[il][c]);
            float m2 = ma - accU[ni][jj];
            u16 hu = f2bf(m2);
            MAh[il][c] = hu;
            MAl[il][c] = f2bf(m2 - bf2f(hu));
        }
    }
    __syncthreads();

    // ---- coalesced store back to [c][i] layout ----
    for (int idx = t; idx < 1024; idx += 512) {
        int c = idx >> 1, ch = idx & 1;
        bf16x8 hv, lv;
#pragma unroll
        for (int j = 0; j < 8; ++j) {
            hv[j] = (short)MAh[ch * 8 + j][c];
            lv[j] = (short)MAl[ch * 8 + j][c];
        }
        *(bf16x8*)(Mth_g + (size_t)c * CH + i_top0 + ch * 8) = hv;
        *(bf16x8*)(Mtl_g + (size_t)c * CH + i_top0 + ch * 8) = lv;
    }
}

// ---------------------------------------------------------------------------
// Kernel 3: Qt[g][d][c] = [I - w*M]^T. 512 blocks (2/CU) x 256 thr.
// 32(M=c) x 128(N=d) tiles, K=512 over i. 4 waves split N.
// ---------------------------------------------------------------------------
__global__ __launch_bounds__(256) void k_qbuild2(const float* __restrict__ w,
                                                 const u16* __restrict__ Mth,
                                                 const u16* __restrict__ Mtl,
                                                 u16* __restrict__ Qt) {
    int t = threadIdx.x, lane = t & 63, wv = t >> 6;
    int fr = lane & 15, kg = lane >> 4;
    int g  = blockIdx.x >> 6;
    int tm = (blockIdx.x >> 2) & 15, tn = blockIdx.x & 3;
    int c0 = tm * 32;
    int d0 = tn * 128 + wv * 32;

    const float* wg = w + (size_t)g * CH * CH;
    const u16* Mth_g = Mth + (size_t)g * CH * CH;
    const u16* Mtl_g = Mtl + (size_t)g * CH * CH;
    u16* Qt_g = Qt + (size_t)g * CH * CH;

    f32x4 acc[2][2];
#pragma unroll
    for (int mi = 0; mi < 2; ++mi)
#pragma unroll
        for (int ni = 0; ni < 2; ++ni)
#pragma unroll
            for (int z = 0; z < 4; ++z) acc[mi][ni][z] = 0.f;

    for (int ks = 0; ks < 16; ++ks) {
        bf16x8 ah[2], al[2], bh[2], bl[2];
#pragma unroll
        for (int mi = 0; mi < 2; ++mi) {
            const float* src = wg + (size_t)(c0 + mi * 16 + fr) * CH + ks * 32 + kg * 8;
            float4 v0 = *(const float4*)src;
            float4 v1 = *(const float4*)(src + 4);
            float a8[8] = {v0.x, v0.y, v0.z, v0.w, v1.x, v1.y, v1.z, v1.w};
            split8(a8, ah[mi], al[mi]);
        }
#pragma unroll
        for (int ni = 0; ni < 2; ++ni) {
            size_t mo = (size_t)(d0 + ni * 16 + fr) * CH + ks * 32 + kg * 8;
            bh[ni] = *(const bf16x8*)(Mth_g + mo);
            bl[ni] = *(const bf16x8*)(Mtl_g + mo);
        }
#pragma unroll
        for (int mi = 0; mi < 2; ++mi)
#pragma unroll
            for (int ni = 0; ni < 2; ++ni) {
                acc[mi][ni] = MFMA(ah[mi], bh[ni], acc[mi][ni]);
                acc[mi][ni] = MFMA(ah[mi], bl[ni], acc[mi][ni]);
                acc[mi][ni] = MFMA(al[mi], bh[ni], acc[mi][ni]);
            }
    }
#pragma unroll
    for (int mi = 0; mi < 2; ++mi)
#pragma unroll
        for (int ni = 0; ni < 2; ++ni) {
            int cb = c0 + mi * 16 + kg * 4;
            int d  = d0 + ni * 16 + fr;
            ushort4 h4;
            h4.x = f2bf(((cb + 0 == d) ? 1.0f : 0.0f) - acc[mi][ni][0]);
            h4.y = f2bf(((cb + 1 == d) ? 1.0f : 0.0f) - acc[mi][ni][1]);
            h4.z = f2bf(((cb + 2 == d) ? 1.0f : 0.0f) - acc[mi][ni][2]);
            h4.w = f2bf(((cb + 3 == d) ? 1.0f : 0.0f) - acc[mi][ni][3]);
            *(ushort4*)(Qt_g + (size_t)d * CH + cb) = h4;
        }
}

// ---------------------------------------------------------------------------
// Kernel 4 (m97-style): out = xb @ Qt^T-as-B; both bf16 staged via
// global_load_lds width-16 into linear LDS [128][32]. 128x128, BK=32.
// ---------------------------------------------------------------------------
__global__ __launch_bounds__(256) void k_gemm2(const u16* __restrict__ xb,
                                               const u16* __restrict__ Qt,
                                               float* __restrict__ out) {
    __shared__ u16 Ab[128 * 32];
    __shared__ u16 Bb[128 * 32];

    int bid = blockIdx.x;
    int g  = bid >> 7;
    int tn = (bid >> 5) & 3;
    int tm = bid & 31;

    int t    = threadIdx.x;
    int lane = t & 63;
    int wv   = t >> 6;
    int wr   = wv >> 1, wc = wv & 1;
    int fr   = lane & 15, kg = lane >> 4;

    const u16* xg  = xb + (size_t)g * BS * CH + (size_t)tm * 128 * CH;
    const u16* Qtg = Qt + (size_t)g * CH * CH + (size_t)tn * 128 * CH;
    float* og = out + (size_t)g * BS * CH + (size_t)tm * 128 * CH + (size_t)tn * 128;

    f32x4 acc[4][4];
#pragma unroll
    for (int mi = 0; mi < 4; ++mi)
#pragma unroll
        for (int ni = 0; ni < 4; ++ni)
#pragma unroll
            for (int z = 0; z < 4; ++z) acc[mi][ni][z] = 0.f;

    int srow = lane >> 2;        // 0..15 within 16-row segment
    int scol = (lane & 3) * 8;   // bf16 elem offset within 32-wide K

    for (int ks = 0; ks < 16; ++ks) {
        int k0 = ks * 32;
        __syncthreads();
#pragma unroll
        for (int si = 0; si < 2; ++si) {
            int s = wv * 2 + si;            // segment 0..7 (16 rows each)
            int row = s * 16 + srow;
            gload16(xg  + (size_t)row * CH + k0 + scol, &Ab[s * 512]);
            gload16(Qtg + (size_t)row * CH + k0 + scol, &Bb[s * 512]);
        }
        __syncthreads();

        bf16x8 af[4], bfr[4];
#pragma unroll
        for (int mi = 0; mi < 4; ++mi)
            af[mi] = *(const bf16x8*)&Ab[(wr * 64 + mi * 16 + fr) * 32 + kg * 8];
#pragma unroll
        for (int ni = 0; ni < 4; ++ni)
            bfr[ni] = *(const bf16x8*)&Bb[(wc * 64 + ni * 16 + fr) * 32 + kg * 8];
#pragma unroll
        for (int mi = 0; mi < 4; ++mi)
#pragma unroll
            for (int ni = 0; ni < 4; ++ni)
                acc[mi][ni] = MFMA(af[mi], bfr[ni], acc[mi][ni]);
    }

    int rg = lane >> 4;
#pragma unroll
    for (int mi = 0; mi < 4; ++mi)
#pragma unroll
        for (int ni = 0; ni < 4; ++ni)
#pragma unroll
            for (int rj = 0; rj < 4; ++rj) {
                int grow = wr * 64 + mi * 16 + rg * 4 + rj;
                int gcol = wc * 64 + ni * 16 + fr;
                og[(size_t)grow * CH + gcol] = acc[mi][ni][rj];
            }
}

// ---------------------------------------------------------------------------
// Fallback GEMM (fp32 A, in-staging convert) — round-5 verified.
// ---------------------------------------------------------------------------
#define LDP 40
__global__ __launch_bounds__(256) void k_gemm_f32(const float* __restrict__ x,
                                                  const u16* __restrict__ Qt,
                                                  float* __restrict__ out) {
    __shared__ u16 Al[128 * LDP];
    __shared__ u16 Bl[128 * LDP];

    int bid = blockIdx.x;
    int g  = bid >> 7;
    int tn = (bid >> 5) & 3;
    int tm = bid & 31;

    int t    = threadIdx.x;
    int lane = t & 63;
    int w    = t >> 6;
    int wr   = w >> 1, wc = w & 1;

    const float* xg = x + (size_t)g * BS * CH + (size_t)tm * 128 * CH;
    const u16* Qtg = Qt + (size_t)g * CH * CH + (size_t)tn * 128 * CH;
    float* og = out + (size_t)g * BS * CH + (size_t)tm * 128 * CH + (size_t)tn * 128;

    f32x4 acc[4][4];
#pragma unroll
    for (int mi = 0; mi < 4; ++mi)
#pragma unroll
        for (int ni = 0; ni < 4; ++ni)
#pragma unroll
            for (int z = 0; z < 4; ++z) acc[mi][ni][z] = 0.f;

    int a_k4 = t & 7;
    int a_r  = t >> 3;
    int b_n  = t & 127;
    int b_kh = t >> 7;
    int fr = lane & 15, kg = lane >> 4;

    for (int ks = 0; ks < 16; ++ks) {
        int k0 = ks * 32;
        __syncthreads();
#pragma unroll
        for (int rr = 0; rr < 4; ++rr) {
            int r = a_r + 32 * rr;
            float4 v = *(const float4*)(xg + (size_t)r * CH + k0 + a_k4 * 4);
            ushort4 h;
            h.x = f2bf(v.x); h.y = f2bf(v.y); h.z = f2bf(v.z); h.w = f2bf(v.w);
            *(ushort4*)(&Al[r * LDP + a_k4 * 4]) = h;
        }
        {
            const u16* src = Qtg + (size_t)b_n * CH + k0 + b_kh * 16;
            u16x8 lo = *(const u16x8*)src;
            u16x8 hi = *(const u16x8*)(src + 8);
            *(u16x8*)(&Bl[b_n * LDP + b_kh * 16]) = lo;
            *(u16x8*)(&Bl[b_n * LDP + b_kh * 16 + 8]) = hi;
        }
        __syncthreads();
        bf16x8 af[4], bfr[4];
#pragma unroll
        for (int mi = 0; mi < 4; ++mi)
            af[mi] = *(const bf16x8*)(&Al[(wr * 64 + mi * 16 + fr) * LDP + kg * 8]);
#pragma unroll
        for (int ni = 0; ni < 4; ++ni)
            bfr[ni] = *(const bf16x8*)(&Bl[(wc * 64 + ni * 16 + fr) * LDP + kg * 8]);
#pragma unroll
        for (int mi = 0; mi < 4; ++mi)
#pragma unroll
            for (int ni = 0; ni < 4; ++ni)
                acc[mi][ni] = MFMA(af[mi], bfr[ni], acc[mi][ni]);
    }

    int rg = lane >> 4;
#pragma unroll
    for (int mi = 0; mi < 4; ++mi)
#pragma unroll
        for (int ni = 0; ni < 4; ++ni)
#pragma unroll
            for (int rj = 0; rj < 4; ++rj) {
                int grow = wr * 64 + mi * 16 + rg * 4 + rj;
                int gcol = wc * 64 + ni * 16 + fr;
                og[(size_t)grow * CH + gcol] = acc[mi][ni][rj];
            }
}

// ---------------------------------------------------------------------------
extern "C" void kernel_launch(void* const* d_in, const int* in_sizes, int n_in,
                              void* d_out, int out_size, void* d_ws, size_t ws_size,
                              hipStream_t stream) {
    const float* x = (const float*)d_in[0];   // (8, 4096, 512)
    const float* w = (const float*)d_in[1];   // (8, 512, 512)
    float* out = (float*)d_out;

    // scratch carved from d_out (64 MiB; dead before GEMM writes it):
    char* ob = (char*)d_out;
    u16* Yh  = (u16*)ob;                      // [0, 4MB)
    u16* Yl  = (u16*)(ob + (4u  << 20));      // [4, 8)
    u16* Mth = (u16*)(ob + (8u  << 20));      // [8, 12)
    u16* Mtl = (u16*)(ob + (12u << 20));      // [12, 16)

    // d_ws: fat = xb (32 MB) + Qt (4 MB); else Qt only.
    int fat = (ws_size >= ((32u << 20) + (4u << 20))) ? 1 : 0;
    u16* xbp = (u16*)d_ws;
    u16* Qt  = fat ? (u16*)((char*)d_ws + (32u << 20)) : (u16*)d_ws;

    k_panelprep<<<dim3(fat ? 1152 : 128), dim3(512), 0, stream>>>(w, x, Yh, Yl, Mth, Mtl, xbp);
    k_combine<32><<<dim3(128), dim3(512), 0, stream>>>(Yh, Yl, Mth, Mtl);
    k_combine<64><<<dim3(128), dim3(512), 0, stream>>>(Yh, Yl, Mth, Mtl);
    k_combine<128><<<dim3(128), dim3(512), 0, stream>>>(Yh, Yl, Mth, Mtl);
    k_combine<256><<<dim3(128), dim3(512), 0, stream>>>(Yh, Yl, Mth, Mtl);
    k_qbuild2<<<dim3(512), dim3(256), 0, stream>>>(w, Mth, Mtl, Qt);
    if (fat)
        k_gemm2<<<dim3(1024), dim3(256), 0, stream>>>(xbp, Qt, out);
    else
        k_gemm_f32<<<dim3(1024), dim3(256), 0, stream>>>(x, Qt, out);
}